// Round 9
// baseline (3565.171 us; speedup 1.0000x reference)
//
#include <hip/hip_runtime.h>
#include <stdint.h>

// ---------------------------------------------------------------------------
// 2-layer LSTM (T=256, B=256, F=128, H=1024) for MI355X (gfx950).
// R15: l0(ch) || l1(ch-1) CONCURRENT in one 512-WG kernel (they are data-
// independent; only stream order serialized them). Each CU hosts one l0-WG
// and one l1-WG (2 WGs/CU) -> 4 waves/SIMD from INDEPENDENT WGs: one WG's
// exchange stall is filled by the other's compute (the occupancy R9's
// lockstep 16-wave WG could not deliver).
// Enablers:
//   - LDS/WG 99.8 -> ~66.5KB (2/CU fits): As 64->32KB via row-half double
//     pump. As holds rows [16p,+16) of all 32 chunks; per step: MFMA pump0
//     -> gbuf(mt0) write -> per-kh rdone counter (4-wave group) -> restage
//     pump1 -> MFMA pump1. hx/hpp re-blocked [chunk][mi][rowhalf][1KB],
//     same R13-verified XOR swizzle within each 1KB (granule 2-way).
//   - disjoint stamp groups (l0: 0-7, l1: 8-15) + disjoint probe tokens.
//   - launch chain: fused(0)[l0] g(0) fused(1)[l0|l1] g(1) ... fused(N)[l1] y.
// gemm = R14's 256^2 4-phase counted-vmcnt kernel (measured ~1450 TF).
// FP accumulation order unchanged -> absmax expected identical.
// ---------------------------------------------------------------------------

typedef __bf16 bf16x8 __attribute__((ext_vector_type(8)));
typedef float  f32x4  __attribute__((ext_vector_type(4)));
typedef unsigned short ushort8v __attribute__((ext_vector_type(8)));
typedef unsigned short ushort4v __attribute__((ext_vector_type(4)));
typedef unsigned short ushort2v __attribute__((ext_vector_type(2)));
typedef __attribute__((address_space(1))) unsigned int as1_u32;
typedef __attribute__((address_space(3))) unsigned int as3_u32;

#define T_STEPS 256
#define BATCH   256
#define HDIM    1024
#define GDIM    4096
#define FDIM    128
#define HXSLOTB (524288)   // bytes per blocked h slot: 32 chunks x 16KB

static __device__ __forceinline__ float bf2f(unsigned short u) {
  union { unsigned int i; float f; } v; v.i = ((unsigned int)u) << 16; return v.f;
}
static __device__ __forceinline__ unsigned short f2bf(float f) {
  return __builtin_bit_cast(unsigned short, (__bf16)f);
}
static __device__ __forceinline__ float sigm(float x) { return 1.f / (1.f + __expf(-x)); }
static __device__ __forceinline__ float tanh_f(float x) { return 2.f / (1.f + __expf(-2.f * x)) - 1.f; }

// 1KB-sub-block bank swizzle (involution): flips byte bits 4-5 by row-pair.
static __device__ __forceinline__ int swz1(int b) {
  return b ^ (((b >> 7) & 3) << 4);
}
// gemm LDS swizzle (involution): flips byte bits 4-6 by row (128B rows).
static __device__ __forceinline__ int gswz(int b) {
  return b ^ (((b >> 7) & 7) << 4);
}

static __device__ __forceinline__ void vl1_inv() {
  asm volatile("buffer_inv" ::: "memory");
}

__global__ void conv_bf16(const float* __restrict__ s, unsigned short* __restrict__ d, int n) {
  int i = blockIdx.x * 256 + threadIdx.x;
  if (i < n) d[i] = f2bf(s[i]);
}

__global__ void diag_kernel(float* out, int n, float v) {
  int i = blockIdx.x * 256 + threadIdx.x;
  if (i < n) out[i] = v;
}

// ------------------------- stamps / polls / flags ----------------------------
__device__ __forceinline__ void post_stamp(unsigned int* st, unsigned int gen, bool fast) {
  if (!fast) __builtin_amdgcn_fence(__ATOMIC_RELEASE, "agent");
  __hip_atomic_store(st, gen, __ATOMIC_RELAXED, __HIP_MEMORY_SCOPE_AGENT);
}

__device__ __forceinline__ void poll_all(unsigned int* stamps, unsigned int target) {
  unsigned int* p = stamps + (threadIdx.x & 31) * 32;
  for (unsigned int it = 0; it < (1u << 15); ++it) {
    unsigned int gv = __hip_atomic_load(p, __ATOMIC_RELAXED, __HIP_MEMORY_SCOPE_AGENT);
    if (__all((int)(gv - target) >= 0)) return;
    if (it > 16) __builtin_amdgcn_s_sleep(1);
  }
}

__device__ __forceinline__ void poll_mine(unsigned int* stamps, int g, int kh, unsigned int target) {
  unsigned int* p = stamps + (kh * 16 + g + 4 * ((int)threadIdx.x & 3)) * 32;
  for (unsigned int it = 0; it < (1u << 15); ++it) {
    unsigned int gv = __hip_atomic_load(p, __ATOMIC_RELAXED, __HIP_MEMORY_SCOPE_AGENT);
    if (__all((int)(gv - target) >= 0)) return;
    if (it > 64) __builtin_amdgcn_s_sleep(1);
  }
}

__device__ __forceinline__ void lds_spin(unsigned int* f, unsigned int need) {
  for (unsigned int it = 0; it < (1u << 15); ++it) {
    unsigned int v = __hip_atomic_load(f, __ATOMIC_ACQUIRE, __HIP_MEMORY_SCOPE_WORKGROUP);
    if ((int)(v - need) >= 0) return;
    if (it > 32) __builtin_amdgcn_s_sleep(1);
  }
}

__device__ __forceinline__ void rdone_spin(unsigned int* f, unsigned int need) {
  for (unsigned int it = 0; it < (1u << 15); ++it) {
    unsigned int v = __hip_atomic_load(f, __ATOMIC_RELAXED, __HIP_MEMORY_SCOPE_WORKGROUP);
    if ((int)(v - need) >= 0) return;
  }
}

// Stage this wave's 4 chunks' row-half p (1KB each, contiguous in blocked h)
// into As (chunk-major, 1KB/chunk) via global_load_lds width-16.
__device__ __forceinline__ void stage_pump(const char* hslotB, unsigned short* AsPtr,
                                           int mi, int g, int kh, int p, int lane) {
  #pragma unroll
  for (int q = 0; q < 4; ++q) {
    int c = kh * 16 + g + 4 * q;
    const char* src = hslotB + (size_t)c * 16384 + mi * 2048 + p * 1024 + lane * 16;
    char* dst = (char*)AsPtr + c * 1024;
    __builtin_amdgcn_global_load_lds((const as1_u32*)src, (as3_u32*)dst, 16, 0, 0);
  }
}

// --------------------------- gemm_bt: C = A @ B^T ---------------------------
// 256^2 tile, 4-phase counted-vmcnt schedule (R14, measured ~1450 TF).
__global__ __launch_bounds__(512, 2) void gemm_bt_xw(
    const unsigned short* __restrict__ A,
    const unsigned short* __restrict__ B,
    unsigned short* __restrict__ xw)
{
  const int tid = threadIdx.x, lane = tid & 63, wv = tid >> 6;   // 8 waves
  const int wm = wv & 1, wn = wv >> 1;                           // 2M x 4N
  const int quad = lane >> 4, l15 = lane & 15;
  const int m0 = blockIdx.x * 256;
  const int n0 = blockIdx.y * 256;

  __shared__ unsigned short Ab[2][16384];
  __shared__ unsigned short Bb[2][16384];

  f32x4 acc[8][4];
  #pragma unroll
  for (int i = 0; i < 8; ++i)
    #pragma unroll
    for (int j = 0; j < 4; ++j) acc[i][j] = f32x4{0.f, 0.f, 0.f, 0.f};

  #define G2L(dst8k, src, row_org, blk_row0, kt_)                                   \
    {                                                                               \
      int o_ = wv * 1024 + lane * 16;                                               \
      int tp_ = gswz(o_);                                                           \
      int row_ = (blk_row0) + (tp_ >> 7);                                           \
      const char* g_ = (const char*)((src) + (size_t)((row_org) + row_) * 1024)     \
                       + (kt_) * 128 + (tp_ & 127);                                 \
      __builtin_amdgcn_global_load_lds((const as1_u32*)g_,                          \
          (as3_u32*)((char*)(dst8k) + wv * 1024), 16, 0, 0);                        \
    }

  #pragma unroll
  for (int b4 = 0; b4 < 4; ++b4) G2L(&Bb[0][b4 * 4096], B, n0, b4 * 64, 0);
  #pragma unroll
  for (int q4 = 0; q4 < 4; ++q4) G2L(&Ab[0][q4 * 4096], A, m0, q4 * 64, 0);
  __syncthreads();

  bf16x8 af[4][2], bfr[4][2];

  #pragma unroll 1
  for (int kt = 0; kt < 16; ++kt) {
    const int cur = kt & 1, nxt = cur ^ 1;
    const bool st = (kt < 15);

    if (st) { G2L(&Bb[nxt][0], B, n0, 0, kt + 1); G2L(&Bb[nxt][4096], B, n0, 64, kt + 1); }
    if (kt == 15)      asm volatile("s_waitcnt vmcnt(2)" ::: "memory");
    else if (kt > 0)   asm volatile("s_waitcnt vmcnt(4)" ::: "memory");
    __builtin_amdgcn_s_barrier();
    __builtin_amdgcn_sched_barrier(0);
    #pragma unroll
    for (int nt = 0; nt < 4; ++nt)
      #pragma unroll
      for (int kk = 0; kk < 2; ++kk) {
        int q = (wn * 64 + nt * 16 + l15) * 128 + kk * 64 + quad * 16;
        bfr[nt][kk] = *(const bf16x8*)((const char*)Bb[cur] + gswz(q));
      }
    #pragma unroll
    for (int mt = 0; mt < 4; ++mt)
      #pragma unroll
      for (int kk = 0; kk < 2; ++kk) {
        int q = (wm * 128 + mt * 16 + l15) * 128 + kk * 64 + quad * 16;
        af[mt][kk] = *(const bf16x8*)((const char*)Ab[cur] + gswz(q));
      }
    __builtin_amdgcn_s_setprio(1);
    #pragma unroll
    for (int mt = 0; mt < 4; ++mt)
      #pragma unroll
      for (int nt = 0; nt < 2; ++nt)
        #pragma unroll
        for (int kk = 0; kk < 2; ++kk)
          acc[mt][nt] = __builtin_amdgcn_mfma_f32_16x16x32_bf16(af[mt][kk], bfr[nt][kk], acc[mt][nt], 0, 0, 0);
    __builtin_amdgcn_s_setprio(0);
    __builtin_amdgcn_s_barrier();

    if (st) { G2L(&Bb[nxt][8192], B, n0, 128, kt + 1); G2L(&Bb[nxt][12288], B, n0, 192, kt + 1); }
    __builtin_amdgcn_s_barrier();
    __builtin_amdgcn_s_setprio(1);
    #pragma unroll
    for (int mt = 0; mt < 4; ++mt)
      #pragma unroll
      for (int nt = 0; nt < 2; ++nt)
        #pragma unroll
        for (int kk = 0; kk < 2; ++kk)
          acc[mt][nt + 2] = __builtin_amdgcn_mfma_f32_16x16x32_bf16(af[mt][kk], bfr[nt + 2][kk], acc[mt][nt + 2], 0, 0, 0);
    __builtin_amdgcn_s_setprio(0);
    __builtin_amdgcn_s_barrier();

    if (st) { G2L(&Ab[nxt][0], A, m0, 0, kt + 1); G2L(&Ab[nxt][8192], A, m0, 128, kt + 1); }
    if (kt == 15) asm volatile("s_waitcnt vmcnt(0)" ::: "memory");
    else          asm volatile("s_waitcnt vmcnt(6)" ::: "memory");
    __builtin_amdgcn_s_barrier();
    __builtin_amdgcn_sched_barrier(0);
    #pragma unroll
    for (int mt = 0; mt < 4; ++mt)
      #pragma unroll
      for (int kk = 0; kk < 2; ++kk) {
        int q = (wm * 128 + 64 + mt * 16 + l15) * 128 + kk * 64 + quad * 16;
        af[mt][kk] = *(const bf16x8*)((const char*)Ab[cur] + gswz(q));
      }
    __builtin_amdgcn_s_setprio(1);
    #pragma unroll
    for (int mt = 0; mt < 4; ++mt)
      #pragma unroll
      for (int nt = 0; nt < 2; ++nt)
        #pragma unroll
        for (int kk = 0; kk < 2; ++kk)
          acc[mt + 4][nt] = __builtin_amdgcn_mfma_f32_16x16x32_bf16(af[mt][kk], bfr[nt][kk], acc[mt + 4][nt], 0, 0, 0);
    __builtin_amdgcn_s_setprio(0);
    __builtin_amdgcn_s_barrier();

    if (st) { G2L(&Ab[nxt][4096], A, m0, 64, kt + 1); G2L(&Ab[nxt][12288], A, m0, 192, kt + 1); }
    __builtin_amdgcn_s_barrier();
    __builtin_amdgcn_s_setprio(1);
    #pragma unroll
    for (int mt = 0; mt < 4; ++mt)
      #pragma unroll
      for (int nt = 0; nt < 2; ++nt)
        #pragma unroll
        for (int kk = 0; kk < 2; ++kk)
          acc[mt + 4][nt + 2] = __builtin_amdgcn_mfma_f32_16x16x32_bf16(af[mt][kk], bfr[nt + 2][kk], acc[mt + 4][nt + 2], 0, 0, 0);
    __builtin_amdgcn_s_setprio(0);
    __builtin_amdgcn_s_barrier();
  }
  #undef G2L

  #pragma unroll
  for (int mt = 0; mt < 8; ++mt) {
    int ml = wm * 128 + mt * 16 + quad * 4;
    #pragma unroll
    for (int nt = 0; nt < 4; ++nt) {
      int col = n0 + wn * 64 + nt * 16 + l15;
      ushort4v v;
      v.x = f2bf(acc[mt][nt][0]); v.y = f2bf(acc[mt][nt][1]);
      v.z = f2bf(acc[mt][nt][2]); v.w = f2bf(acc[mt][nt][3]);
      *(ushort4v*)(xw + ((size_t)blockIdx.x * GDIM + col) * BATCH + ml) = v;
    }
  }
}

// ---------------- probe: validate intra-XCD visibility for this group --------
__device__ __forceinline__ bool probe_chk(unsigned int* probeBuf, unsigned int* stamps,
                                          unsigned int salt, unsigned int target,
                                          unsigned int* flagLds, int tokIdx, int tokBase, int mi, int ni) {
  const int tid = threadIdx.x;
  if (tid == 0) probeBuf[tokIdx * 32] = salt ^ (unsigned int)tokIdx;
  __syncthreads();   // drains token store to L2; also orders shared-mem init
  if (tid == 0)
    __hip_atomic_store(stamps + ni * 32, target, __ATOMIC_RELAXED, __HIP_MEMORY_SCOPE_AGENT);
  poll_all(stamps, target);
  vl1_inv();
  if (tid == 0) {
    unsigned int bad = 0;
    for (int k = 0; k < 32; ++k) {
      int member = tokBase + mi + 8 * k;
      unsigned int v = probeBuf[member * 32];
      if (v != (salt ^ (unsigned int)member)) bad = 1;
    }
    *flagLds = bad;
  }
  __syncthreads();
  return (*flagLds == 0);
}

// --------------------------- recurrent body (both layers) --------------------
// WG (mi, ni): rows [32mi,+32), cols [32ni,+32). Wave wv: gate g=wv&3,
// K-half kh=wv>>2. whh[2][16] slots in consume order. Row-half double-pump.
template<bool L1>
__device__ __forceinline__ void lstm_body(
    const unsigned short* __restrict__ xin,   // l0: xbf (T,B,F); l1: xw
    const float* __restrict__ Wih,            // l0 only
    const float* __restrict__ Whh,
    const float* __restrict__ bih,
    const float* __restrict__ bhh,
    unsigned short* __restrict__ slab,        // l0 only (row-major gemm feed)
    unsigned short* __restrict__ hexch,       // blocked+swizzled 2-slot ping-pong
    float* __restrict__ cstate,
    unsigned short* __restrict__ h1t0,        // l1 only
    float* __restrict__ dout_h,
    float* __restrict__ dout_c,
    int t0, int ch_len, unsigned int gen_base,
    unsigned int* __restrict__ stamps,
    unsigned int* __restrict__ probeBuf, int tokIdx, int tokBase,
    int mi, int ni,
    unsigned short* As, float (*gbuf)[32][33],
    unsigned int (*cflag)[8], unsigned int* rdone, unsigned int* flagLds)
{
  const int tid = threadIdx.x, lane = tid & 63, wv = tid >> 6;
  const int quad = lane >> 4, l15 = lane & 15;
  const int g = wv & 3, kh = wv >> 2;
  const int r0 = mi * 32, hc0 = ni * 32;
  const int aoff = swz1(l15 * 64 + quad * 16);   // lane-const swizzled read offset

  // W_hh fragment, slots permuted into consume order.
  bf16x8 whh[2][16];
  #pragma unroll
  for (int nt = 0; nt < 2; ++nt) {
    #pragma unroll
    for (int sl = 0; sl < 16; ++sl) {
      int jj = ((g + (sl >> 2)) & 3) + 4 * (sl & 3);
      const float* wrow = Whh + (size_t)(g * HDIM + hc0 + nt * 16 + l15) * HDIM + kh * 512 + jj * 32 + quad * 8;
      f32x4 f0 = *(const f32x4*)(wrow);
      f32x4 f1 = *(const f32x4*)(wrow + 4);
      bf16x8 r;
      r[0] = (__bf16)f0[0]; r[1] = (__bf16)f0[1]; r[2] = (__bf16)f0[2]; r[3] = (__bf16)f0[3];
      r[4] = (__bf16)f1[0]; r[5] = (__bf16)f1[1]; r[6] = (__bf16)f1[2]; r[7] = (__bf16)f1[3];
      whh[nt][sl] = r;
    }
  }
  bf16x8 wih[2][2];
  if constexpr (!L1) {
    #pragma unroll
    for (int nt = 0; nt < 2; ++nt) {
      const float* wrow = Wih + (size_t)(g * HDIM + hc0 + nt * 16 + l15) * FDIM + kh * 64 + quad * 8;
      #pragma unroll
      for (int kk = 0; kk < 2; ++kk) {
        f32x4 f0 = *(const f32x4*)(wrow + kk * 32);
        f32x4 f1 = *(const f32x4*)(wrow + kk * 32 + 4);
        bf16x8 r;
        r[0] = (__bf16)f0[0]; r[1] = (__bf16)f0[1]; r[2] = (__bf16)f0[2]; r[3] = (__bf16)f0[3];
        r[4] = (__bf16)f1[0]; r[5] = (__bf16)f1[1]; r[6] = (__bf16)f1[2]; r[7] = (__bf16)f1[3];
        wih[nt][kk] = r;
      }
    }
  }

  const int hcl = tid & 31, rg2 = tid >> 5;
  float bias[4];
  #pragma unroll
  for (int b4 = 0; b4 < 4; ++b4)
    bias[b4] = bih[b4 * HDIM + hc0 + hcl] + bhh[b4 * HDIM + hc0 + hcl];

  float c[2];
  #pragma unroll
  for (int r = 0; r < 2; ++r)
    c[r] = (t0 == 0) ? 0.f : cstate[(size_t)(r0 + rg2 * 2 + r) * HDIM + hc0 + hcl];

  unsigned int salt = (L1 ? 0xB5297A4Du : 0x9E3779B9u) ^ (gen_base * 2654435761u);
  bool fast = probe_chk(probeBuf, stamps, salt, gen_base + 1u, flagLds, tokIdx, tokBase, mi, ni);

  const int tend = t0 + ch_len;

  // prologue: stage pump0 from previous chunk's h (cross-kernel, stream-visible)
  if (t0 > 0) {
    stage_pump((const char*)hexch + (size_t)((t0 - 1) & 1) * HXSLOTB, As, mi, g, kh, 0, lane);
    asm volatile("s_waitcnt vmcnt(0)" ::: "memory");
    if (lane == 0)
      __hip_atomic_store(&cflag[0][kh * 4 + g], gen_base + 1u, __ATOMIC_RELEASE, __HIP_MEMORY_SCOPE_WORKGROUP);
  }

  // prologue: x contribution for the first step
  f32x4 acc[2][2];
  #pragma unroll
  for (int mt = 0; mt < 2; ++mt)
    #pragma unroll
    for (int nt = 0; nt < 2; ++nt) acc[mt][nt] = f32x4{0.f, 0.f, 0.f, 0.f};
  float xwv[4][2];
  if constexpr (!L1) {
    #pragma unroll
    for (int j = 0; j < 2; ++j) {
      bf16x8 af[2];
      #pragma unroll
      for (int mt = 0; mt < 2; ++mt)
        af[mt] = *(const bf16x8*)(xin + (size_t)(t0 * BATCH + r0 + mt * 16 + l15) * FDIM + kh * 64 + j * 32 + quad * 8);
      #pragma unroll
      for (int mt = 0; mt < 2; ++mt)
        #pragma unroll
        for (int nt = 0; nt < 2; ++nt)
          acc[mt][nt] = __builtin_amdgcn_mfma_f32_16x16x32_bf16(af[mt], wih[nt][j], acc[mt][nt], 0, 0, 0);
    }
  } else {
    #pragma unroll
    for (int g4 = 0; g4 < 4; ++g4) {
      const unsigned short* xp = xin + ((size_t)0 * GDIM + g4 * HDIM + hc0 + hcl) * BATCH + r0 + rg2 * 2;
      ushort2v u = *(const ushort2v*)xp;
      xwv[g4][0] = bf2f(u.x); xwv[g4][1] = bf2f(u.y);
    }
  }

  unsigned int pumptgt = 0;

  #pragma unroll 1
  for (int t = t0; t < tend; ++t) {
    if (t > 0) {
      const unsigned int need = gen_base + 1u + (unsigned int)(t - t0);
      // ---- pump 0: rows [r0, r0+16)
      #pragma unroll
      for (int sl = 0; sl < 16; ++sl) {
        const int s = sl >> 2, q = sl & 3;
        int sg = (g + s) & 3;
        if (q == 0 && s > 0) lds_spin(&cflag[0][kh * 4 + sg], need);
        int cidx = kh * 16 + sg + 4 * q;
        bf16x8 af = *(const bf16x8*)((const char*)As + cidx * 1024 + aoff);
        acc[0][0] = __builtin_amdgcn_mfma_f32_16x16x32_bf16(af, whh[0][sl], acc[0][0], 0, 0, 0);
        acc[0][1] = __builtin_amdgcn_mfma_f32_16x16x32_bf16(af, whh[1][sl], acc[0][1], 0, 0, 0);
      }
      // gbuf mt0 early (shadows the pump-1 restage)
      #pragma unroll
      for (int nt = 0; nt < 2; ++nt)
        #pragma unroll
        for (int i = 0; i < 4; ++i)
          gbuf[wv][nt * 16 + l15][quad * 4 + i] = acc[0][nt][i];
      // group-local readers-done; then restage pump 1 into same As
      if (lane == 0)
        __hip_atomic_fetch_add(&rdone[kh], 1u, __ATOMIC_RELAXED, __HIP_MEMORY_SCOPE_WORKGROUP);
      pumptgt += 4;
      rdone_spin(&rdone[kh], pumptgt);
      stage_pump((const char*)hexch + (size_t)((t - 1) & 1) * HXSLOTB, As, mi, g, kh, 1, lane);
      asm volatile("s_waitcnt vmcnt(0)" ::: "memory");
      if (lane == 0)
        __hip_atomic_store(&cflag[1][kh * 4 + g], need, __ATOMIC_RELEASE, __HIP_MEMORY_SCOPE_WORKGROUP);
      // ---- pump 1: rows [r0+16, r0+32)
      #pragma unroll
      for (int sl = 0; sl < 16; ++sl) {
        const int s = sl >> 2, q = sl & 3;
        int sg = (g + s) & 3;
        if (q == 0 && s > 0) lds_spin(&cflag[1][kh * 4 + sg], need);
        int cidx = kh * 16 + sg + 4 * q;
        bf16x8 af = *(const bf16x8*)((const char*)As + cidx * 1024 + aoff);
        acc[1][0] = __builtin_amdgcn_mfma_f32_16x16x32_bf16(af, whh[0][sl], acc[1][0], 0, 0, 0);
        acc[1][1] = __builtin_amdgcn_mfma_f32_16x16x32_bf16(af, whh[1][sl], acc[1][1], 0, 0, 0);
      }
    } else {
      // t == 0: acc holds only the x contribution; write mt0 here.
      #pragma unroll
      for (int nt = 0; nt < 2; ++nt)
        #pragma unroll
        for (int i = 0; i < 4; ++i)
          gbuf[wv][nt * 16 + l15][quad * 4 + i] = acc[0][nt][i];
    }
    // gbuf mt1
    #pragma unroll
    for (int nt = 0; nt < 2; ++nt)
      #pragma unroll
      for (int i = 0; i < 4; ++i)
        gbuf[wv][nt * 16 + l15][16 + quad * 4 + i] = acc[1][nt][i];
    __syncthreads();   // (A) gbuf visible; all As reads of step t complete

    char* hxdB = (char*)hexch + (size_t)(t & 1) * HXSLOTB;
    unsigned short* hdst = nullptr;
    if constexpr (!L1) hdst = slab + (size_t)(t - t0 + 1) * (BATCH * HDIM);
    #pragma unroll
    for (int r = 0; r < 2; ++r) {
      int row = rg2 * 2 + r;
      float gi = gbuf[0][hcl][row] + gbuf[4][hcl][row] + bias[0];
      float gf = gbuf[1][hcl][row] + gbuf[5][hcl][row] + bias[1];
      float gg = gbuf[2][hcl][row] + gbuf[6][hcl][row] + bias[2];
      float go = gbuf[3][hcl][row] + gbuf[7][hcl][row] + bias[3];
      if constexpr (L1) {
        gi += xwv[0][r]; gf += xwv[1][r]; gg += xwv[2][r]; go += xwv[3][r];
      }
      float iv = sigm(gi), fv = sigm(gf), gv = tanh_f(gg), ov = sigm(go);
      float cn = fv * c[r] + iv * gv;
      c[r] = cn;
      float hv = ov * tanh_f(cn);
      unsigned short hb = f2bf(hv);
      int boff = swz1((row & 15) * 64 + hcl * 2);
      *(unsigned short*)(hxdB + (size_t)ni * 16384 + mi * 2048 + (row >> 4) * 1024 + boff) = hb;
      int gidx = (r0 + row) * HDIM + hc0 + hcl;
      if constexpr (!L1) hdst[gidx] = hb;
      if constexpr (L1) { if (h1t0 != nullptr && t == 0) h1t0[gidx] = hb; }
      if (t == tend - 1) cstate[gidx] = cn;
      if (t == T_STEPS - 1) { dout_h[gidx] = hv; dout_c[gidx] = cn; }
    }
    __syncthreads();   // (B) drains h stores -> visible at L2

    if (t != tend - 1) {
      const unsigned int tgt = gen_base + 2u + (unsigned int)(t - t0);
      if (tid == 0) post_stamp(stamps + ni * 32, tgt, fast);

      // hoisted x contribution for step t+1 (independent of h(t))
      #pragma unroll
      for (int mt = 0; mt < 2; ++mt)
        #pragma unroll
        for (int nt = 0; nt < 2; ++nt) acc[mt][nt] = f32x4{0.f, 0.f, 0.f, 0.f};
      if constexpr (!L1) {
        #pragma unroll
        for (int j = 0; j < 2; ++j) {
          bf16x8 af[2];
          #pragma unroll
          for (int mt = 0; mt < 2; ++mt)
            af[mt] = *(const bf16x8*)(xin + (size_t)((t + 1) * BATCH + r0 + mt * 16 + l15) * FDIM + kh * 64 + j * 32 + quad * 8);
          #pragma unroll
          for (int mt = 0; mt < 2; ++mt)
            #pragma unroll
            for (int nt = 0; nt < 2; ++nt)
              acc[mt][nt] = __builtin_amdgcn_mfma_f32_16x16x32_bf16(af[mt], wih[nt][j], acc[mt][nt], 0, 0, 0);
        }
      } else {
        #pragma unroll
        for (int g4 = 0; g4 < 4; ++g4) {
          const unsigned short* xp = xin + ((size_t)(t + 1 - t0) * GDIM + g4 * HDIM + hc0 + hcl) * BATCH + r0 + rg2 * 2;
          ushort2v u = *(const ushort2v*)xp;
          xwv[g4][0] = bf2f(u.x); xwv[g4][1] = bf2f(u.y);
        }
      }

      // exchange: wait only for MY 4 producers, stage pump0(t+1), flag.
      poll_mine(stamps, g, kh, tgt);
      if (fast) vl1_inv();
      else __builtin_amdgcn_fence(__ATOMIC_ACQUIRE, "agent");
      stage_pump((const char*)hexch + (size_t)(t & 1) * HXSLOTB, As, mi, g, kh, 0, lane);
      asm volatile("s_waitcnt vmcnt(0)" ::: "memory");
      if (lane == 0)
        __hip_atomic_store(&cflag[0][kh * 4 + g], tgt, __ATOMIC_RELEASE, __HIP_MEMORY_SCOPE_WORKGROUP);
    }
  }
}

// --------------------------- fused kernel (l0 || l1) -------------------------
// blocks 0..255: l0 chunk (if t0_0 >= 0); blocks 256..511: l1 chunk (t0_1).
__global__ __launch_bounds__(512, 2) void lstm_fused(
    const unsigned short* __restrict__ xbf,
    const float* __restrict__ Wih0, const float* __restrict__ Whh0,
    const float* __restrict__ bih0, const float* __restrict__ bhh0,
    unsigned short* __restrict__ slab, unsigned short* __restrict__ hx,
    float* __restrict__ c0st,
    const unsigned short* __restrict__ xw, const float* __restrict__ Whh1,
    const float* __restrict__ bih1, const float* __restrict__ bhh1,
    unsigned short* __restrict__ hpp, float* __restrict__ c1st,
    unsigned short* __restrict__ h1t0,
    float* __restrict__ hn0, float* __restrict__ cn0,
    float* __restrict__ hn1, float* __restrict__ cn1,
    unsigned int* __restrict__ bar, unsigned int* __restrict__ probe,
    int t0_0, int t0_1, int ch_len, unsigned int gen0, unsigned int gen1)
{
  __shared__ unsigned short As[32 * 512];     // 32KB: 32 chunks x 1KB (row-half)
  __shared__ float gbuf[8][32][33];
  __shared__ unsigned int cflag[2][8];
  __shared__ unsigned int rdone[4];
  __shared__ unsigned int flagLds;

  const int tid = threadIdx.x;
  if (tid < 16) ((unsigned int*)cflag)[tid] = 0;
  if (tid < 4) rdone[tid] = 0;
  // (ordered before use by the __syncthreads inside probe_chk)

  const int bx = blockIdx.x;
  if (bx < 256) {
    if (t0_0 < 0) return;
    const int mi = bx & 7, ni = bx >> 3;
    lstm_body<false>(xbf, Wih0, Whh0, bih0, bhh0, slab, hx, c0st, nullptr,
                     hn0, cn0, t0_0, ch_len, gen0,
                     bar + mi * 1024, probe, bx, 0, mi, ni,
                     As, gbuf, cflag, rdone, &flagLds);
  } else {
    if (t0_1 < 0) return;
    const int wg = bx - 256;
    const int mi = wg & 7, ni = wg >> 3;
    lstm_body<true>(xw, nullptr, Whh1, bih1, bhh1, nullptr, hpp, c1st, h1t0,
                    hn1, cn1, t0_1, ch_len, gen1,
                    bar + (8 + mi) * 1024, probe, bx, 256, mi, ni,
                    As, gbuf, cflag, rdone, &flagLds);
  }
}

__global__ void y_kernel(const unsigned short* __restrict__ h1t0,
                         const unsigned short* __restrict__ wlin,
                         const float* __restrict__ blin,
                         float* __restrict__ y)
{
  int b = blockIdx.x;
  int f = threadIdx.x;
  const ushort8v* hp = (const ushort8v*)(h1t0 + (size_t)b * HDIM);
  const ushort8v* wp = (const ushort8v*)(wlin + (size_t)f * HDIM);
  float acc = 0.f;
  for (int i = 0; i < HDIM / 8; ++i) {
    ushort8v hv = hp[i], wvv = wp[i];
    #pragma unroll
    for (int j = 0; j < 8; ++j) acc += bf2f(hv[j]) * bf2f(wvv[j]);
  }
  y[b * FDIM + f] = acc + blin[f];
}

// ---------------------------------------------------------------------------
extern "C" void kernel_launch(void* const* d_in, const int* in_sizes, int n_in,
                              void* d_out, int out_size, void* d_ws, size_t ws_size,
                              hipStream_t stream) {
  (void)in_sizes; (void)n_in; (void)out_size;
  const float* x    = (const float*)d_in[0];
  const float* Wih0 = (const float*)d_in[1];
  const float* Whh0 = (const float*)d_in[2];
  const float* bih0 = (const float*)d_in[3];
  const float* bhh0 = (const float*)d_in[4];
  const float* Wih1 = (const float*)d_in[5];
  const float* Whh1 = (const float*)d_in[6];
  const float* bih1 = (const float*)d_in[7];
  const float* bhh1 = (const float*)d_in[8];
  const float* Wlin = (const float*)d_in[9];
  const float* blin = (const float*)d_in[10];
  float* out = (float*)d_out;

  const size_t SZ_BAR   = 65536;   // 16 groups x 32 stamps x 128B
  const size_t SZ_PROBE = 65536;   // 512 tokens x 128B
  const size_t SZ_XBF   = (size_t)T_STEPS * BATCH * FDIM * 2;
  const size_t SZ_WIH1  = (size_t)GDIM * HDIM * 2;
  const size_t SZ_WLIN  = (size_t)FDIM * HDIM * 2;
  const size_t SZ_HPP   = (size_t)2 * BATCH * HDIM * 2;
  const size_t SZ_HX    = (size_t)2 * BATCH * HDIM * 2;
  const size_t SZ_H1T0  = (size_t)BATCH * HDIM * 2;
  const size_t SZ_CST   = (size_t)BATCH * HDIM * 4;
  const size_t SLOT     = (size_t)BATCH * HDIM * 2;
  const size_t fixed = SZ_BAR + SZ_PROBE + SZ_XBF + SZ_WIH1 + SZ_WLIN + SZ_HPP + SZ_HX + SZ_H1T0 + 2 * SZ_CST;

  int CH = 0;
  const int cands[7] = {256, 128, 64, 32, 16, 8, 4};
  for (int i = 0; i < 7; ++i) {
    int c = cands[i];
    size_t need = fixed + (size_t)(c + 1) * SLOT + (size_t)c * GDIM * BATCH * 2;
    if (need <= ws_size) { CH = c; break; }
  }
  if (CH == 0 || CH == 256) CH = (CH == 256) ? 128 : 0;  // need >=2 chunks for overlap; 256 would be single-chunk
  if (CH == 0) {
    float v = 1.0e6f + (float)(ws_size >> 20);
    diag_kernel<<<(32768 + 255) / 256, 256, 0, stream>>>(out, 32768, v);
    return;
  }

  char* ws = (char*)d_ws;
  size_t o = 0;
  unsigned int*   bar   = (unsigned int*)(ws + o);    o += SZ_BAR;
  unsigned int*   probe = (unsigned int*)(ws + o);    o += SZ_PROBE;
  unsigned short* xbf   = (unsigned short*)(ws + o);  o += SZ_XBF;
  unsigned short* wih1b = (unsigned short*)(ws + o);  o += SZ_WIH1;
  unsigned short* wlinb = (unsigned short*)(ws + o);  o += SZ_WLIN;
  unsigned short* h1pp  = (unsigned short*)(ws + o);  o += SZ_HPP;
  unsigned short* hx0   = (unsigned short*)(ws + o);  o += SZ_HX;
  unsigned short* h1t0  = (unsigned short*)(ws + o);  o += SZ_H1T0;
  float*          c0st  = (float*)(ws + o);           o += SZ_CST;
  float*          c1st  = (float*)(ws + o);           o += SZ_CST;
  unsigned short* slab  = (unsigned short*)(ws + o);  o += (size_t)(CH + 1) * SLOT;
  unsigned short* xw1   = (unsigned short*)(ws + o);  o += (size_t)CH * GDIM * BATCH * 2;

  hipMemsetAsync(bar, 0, SZ_BAR, stream);

  conv_bf16<<<(T_STEPS * BATCH * FDIM + 255) / 256, 256, 0, stream>>>(x, xbf, T_STEPS * BATCH * FDIM);
  conv_bf16<<<(GDIM * HDIM + 255) / 256, 256, 0, stream>>>(Wih1, wih1b, GDIM * HDIM);
  conv_bf16<<<(FDIM * HDIM + 255) / 256, 256, 0, stream>>>(Wlin, wlinb, FDIM * HDIM);

  float* hn0 = out + 32768;
  float* hn1 = out + 32768 + 262144;
  float* cn0 = out + 32768 + 524288;
  float* cn1 = out + 32768 + 524288 + 262144;

  const int NCH = T_STEPS / CH;
  for (int ch = 0; ch <= NCH; ++ch) {
    int t0_0 = (ch < NCH) ? ch * CH : -1;
    int t0_1 = (ch >= 1) ? (ch - 1) * CH : -1;
    unsigned int gen0 = (unsigned int)(ch * CH);
    unsigned int gen1 = (ch >= 1) ? (unsigned int)((ch - 1) * CH) : 0u;
    lstm_fused<<<512, 512, 0, stream>>>(
        xbf, Wih0, Whh0, bih0, bhh0, slab, hx0, c0st,
        xw1, Whh1, bih1, bhh1, h1pp, c1st, h1t0,
        hn0, cn0, hn1, cn1, bar, probe,
        t0_0, t0_1, CH, gen0, gen1);
    if (ch < NCH)
      gemm_bt_xw<<<dim3(CH, 16), 512, 0, stream>>>(slab + BATCH * HDIM, wih1b, xw1);
  }

  y_kernel<<<256, 128, 0, stream>>>(h1t0, wlinb, blin, out);
}